// Round 4
// baseline (131.681 us; speedup 1.0000x reference)
//
#include <hip/hip_runtime.h>

#define IMG_W 256
#define IMG_H 256
#define EPSN 1e-7f
#define INV_SIG2 50.0f      // 1 / (2 * 0.1^2)
#define NB 16               // batch
#define NN 64               // strokes per image
#define NC 3                // channels
#define PH 32
#define PW 32
#define WIN 36              // stroke footprint window (all nonzero f32 taps)
#define ROWP 36             // padded LDS row stride

#define TILE_W 64
#define TILE_H 16
#define TX_N (IMG_W / TILE_W)   // 4
#define TY_N (IMG_H / TILE_H)   // 16

// ws layout
#define WS_GXY_OFF 0
#define WS_T_OFF   8192                                   // float2 gxy[1024]
#define WS_T_SIZE  ((size_t)NB * NN * NC * WIN * PW * 4)  // 14.2 MB
#define WS_FY_OFF  (WS_T_OFF + WS_T_SIZE)
// fy: [stroke][yl][p]  1024*36*32 f32 = 4.7 MB

// ---------------- kernel 1: per-image min/max normalization ----------------
__global__ __launch_bounds__(64)
void norm_kernel(const float* __restrict__ brushes, float2* __restrict__ gxy) {
    int b = blockIdx.x;
    int n = threadIdx.x;          // one wave == 64 lanes == N strokes
    float x = brushes[(b * NN + n) * 2 + 0];
    float y = brushes[(b * NN + n) * 2 + 1];
    float mnx = x, mxx = x, mny = y, mxy = y;
    #pragma unroll
    for (int off = 32; off > 0; off >>= 1) {
        mnx = fminf(mnx, __shfl_xor(mnx, off));
        mxx = fmaxf(mxx, __shfl_xor(mxx, off));
        mny = fminf(mny, __shfl_xor(mny, off));
        mxy = fmaxf(mxy, __shfl_xor(mxy, off));
    }
    float gx = (x - mnx) / (mxx - mnx + EPSN) * (float)IMG_W;
    float gy = (y - mny) / (mxy - mny + EPSN) * (float)IMG_H;
    gxy[b * NN + n] = make_float2(gx, gy);
}

// ---------------- kernel 2: per-stroke precompute of t and Fy --------------
// t[c][xl][p] = sum_q Fx[xl][q] * patch[c][p][q]   (stage C)
// fy[yl][p]   = Fy window row, scaled by den_y and 1/N
__global__ __launch_bounds__(128)
void precomp_kernel(const float* __restrict__ patches,
                    const float2* __restrict__ gxy,
                    float* __restrict__ t_ws,
                    float* __restrict__ fy_ws) {
    __shared__ float patch_s[NC][PH][ROWP];
    __shared__ float den_x[PW];
    __shared__ float den_y[PH];

    const int blk = blockIdx.x;               // stroke index b*64+n
    const int tid = threadIdx.x;
    const float* P = patches + (size_t)blk * (NC * PH * PW);

    const float2 g = gxy[blk];
    const float gx = g.x, gy = g.y;
    const int ix0 = (int)floorf(gx) - 17;
    const int iy0 = (int)floorf(gy) - 17;

    // stage patch -> LDS (float4, rows padded)
    for (int i = tid; i < NC * PH * PW / 4; i += 128) {
        float4 v = ((const float4*)P)[i];
        int base = i * 4;
        int c = base >> 10;
        int r = base & 1023;
        int p = r >> 5, q = r & 31;
        *(float4*)&patch_s[c][p][q] = v;
    }

    // normalization denominators (4 taps hold all nonzero f32 terms)
    if (tid < PW) {
        float cx = gx + (float)tid - 15.5f;   // ux_q = gx + (q+1) - 16.5
        int f = (int)floorf(cx);
        float s = 0.f;
        #pragma unroll
        for (int t = -1; t <= 2; ++t) {
            int a = f + t;
            if (a >= -16 && a <= IMG_W + 15) {
                float d = (float)a - cx;
                s += expf(-(d * d) * INV_SIG2);
            }
        }
        den_x[tid] = 1.f / (s + EPSN);
    } else if (tid < 2 * PW) {
        int p = tid - PW;
        float cy = gy + (float)p - 15.4f;     // uy_p = gy + (p+1) - 16.4
        int f = (int)floorf(cy);
        float s = 0.f;
        #pragma unroll
        for (int t = -1; t <= 2; ++t) {
            int a = f + t;
            if (a >= -16 && a <= IMG_H + 15) {
                float d = (float)a - cy;
                s += expf(-(d * d) * INV_SIG2);
            }
        }
        den_y[p] = 1.f / (s + EPSN);
    }
    __syncthreads();

    // Fy window rows -> ws (scaled by den_y and 1/N), coalesced
    float* fyb = fy_ws + (size_t)blk * (WIN * PH);
    for (int i = tid; i < WIN * PH; i += 128) {
        int yl = i >> 5, p = i & 31;
        float cy = gy + (float)p - 15.4f;
        float d = (float)(iy0 + yl) - cy;
        fyb[i] = expf(-(d * d) * INV_SIG2) * den_y[p] * (1.0f / (float)NN);
    }

    // stage C: thread owns (c, xl); t row fully in registers, then one
    // contiguous 128B write per thread (coalesced).
    if (tid < NC * WIN) {
        const int cc = tid / WIN;
        const int xl = tid - cc * WIN;
        const int ax = ix0 + xl;              // may be out of image: still computed,
                                              // gather never reads those columns
        float fx[PW];
        #pragma unroll
        for (int q = 0; q < PW; ++q) {
            float d = (float)ax - (gx + (float)q - 15.5f);
            fx[q] = expf(-(d * d) * INV_SIG2) * den_x[q];
        }

        float tr[PH];
        #pragma unroll
        for (int p = 0; p < PH; ++p) {
            const float4* row = (const float4*)&patch_s[cc][p][0];
            float a0 = 0.f, a1 = 0.f, a2 = 0.f, a3 = 0.f;
            #pragma unroll
            for (int q4 = 0; q4 < PW / 4; ++q4) {
                float4 v = row[q4];
                a0 += fx[q4 * 4 + 0] * v.x;
                a1 += fx[q4 * 4 + 1] * v.y;
                a2 += fx[q4 * 4 + 2] * v.z;
                a3 += fx[q4 * 4 + 3] * v.w;
            }
            tr[p] = (a0 + a1) + (a2 + a3);
        }

        float4* dst = (float4*)(t_ws + ((size_t)blk * NC * WIN + tid) * PW);
        #pragma unroll
        for (int p4 = 0; p4 < PH / 4; ++p4)
            dst[p4] = make_float4(tr[p4 * 4 + 0], tr[p4 * 4 + 1],
                                  tr[p4 * 4 + 2], tr[p4 * 4 + 3]);
    }
}

// ---------------- kernel 3: gather per output tile, zero atomics -----------
// Block = one 64x16 tile of one image. Thread owns (c, x) column, acc[16]
// in registers (all statically indexed). Tiles partition the image -> every
// output element written exactly once; no zero-fill kernel needed.
__global__ __launch_bounds__(192)
void gather_kernel(const float2* __restrict__ gxy,
                   const float* __restrict__ t_ws,
                   const float* __restrict__ fy_ws,
                   float* __restrict__ out) {
    const int blk = blockIdx.x;
    const int b   = blk >> 6;                 // image
    const int t6  = blk & 63;
    const int ty0 = (t6 >> 2) * TILE_H;
    const int tx0 = (t6 & 3) * TILE_W;

    const int tid = threadIdx.x;
    const int cc  = tid >> 6;                 // channel 0..2
    const int xg  = tx0 + (tid & 63);         // global x owned by this thread

    float acc[TILE_H];
    #pragma unroll
    for (int i = 0; i < TILE_H; ++i) acc[i] = 0.f;

    const float2* gb = gxy + b * NN;
    for (int n = 0; n < NN; ++n) {
        float2 g = gb[n];
        int ix0 = (int)floorf(g.x) - 17;
        int iy0 = (int)floorf(g.y) - 17;
        // block-uniform overlap test
        if (ix0 > tx0 + TILE_W - 1 || ix0 + WIN - 1 < tx0 ||
            iy0 > ty0 + TILE_H - 1 || iy0 + WIN - 1 < ty0) continue;

        int xl = xg - ix0;
        if ((unsigned)xl < (unsigned)WIN) {
            // stroke's t column for (c, xl): 32 floats, 8x float4 (L1/L2)
            const float4* tp = (const float4*)
                (t_ws + (((size_t)(b * NN + n) * NC + cc) * WIN + xl) * PW);
            float4 tv0 = tp[0], tv1 = tp[1], tv2 = tp[2], tv3 = tp[3];
            float4 tv4 = tp[4], tv5 = tp[5], tv6 = tp[6], tv7 = tp[7];

            const float* fyb = fy_ws + (size_t)(b * NN + n) * (WIN * PH);
            #pragma unroll
            for (int yi = 0; yi < TILE_H; ++yi) {
                int yl = ty0 + yi - iy0;      // block-uniform
                if ((unsigned)yl < (unsigned)WIN) {
                    const float4* fr = (const float4*)(fyb + yl * PH);
                    float4 f0 = fr[0], f1 = fr[1], f2 = fr[2], f3 = fr[3];
                    float4 f4 = fr[4], f5 = fr[5], f6 = fr[6], f7 = fr[7];
                    float a0 = f0.x*tv0.x + f0.y*tv0.y + f0.z*tv0.z + f0.w*tv0.w;
                    float a1 = f1.x*tv1.x + f1.y*tv1.y + f1.z*tv1.z + f1.w*tv1.w;
                    float a2 = f2.x*tv2.x + f2.y*tv2.y + f2.z*tv2.z + f2.w*tv2.w;
                    float a3 = f3.x*tv3.x + f3.y*tv3.y + f3.z*tv3.z + f3.w*tv3.w;
                    a0 += f4.x*tv4.x + f4.y*tv4.y + f4.z*tv4.z + f4.w*tv4.w;
                    a1 += f5.x*tv5.x + f5.y*tv5.y + f5.z*tv5.z + f5.w*tv5.w;
                    a2 += f6.x*tv6.x + f6.y*tv6.y + f6.z*tv6.z + f6.w*tv6.w;
                    a3 += f7.x*tv7.x + f7.y*tv7.y + f7.z*tv7.z + f7.w*tv7.w;
                    acc[yi] += (a0 + a1) + (a2 + a3);
                }
            }
        }
    }

    // coalesced final store: lanes = consecutive x
    float* o = out + (((size_t)b * NC + cc) * IMG_H + ty0) * IMG_W + xg;
    #pragma unroll
    for (int yi = 0; yi < TILE_H; ++yi)
        o[(size_t)yi * IMG_W] = acc[yi];
}

extern "C" void kernel_launch(void* const* d_in, const int* in_sizes, int n_in,
                              void* d_out, int out_size, void* d_ws, size_t ws_size,
                              hipStream_t stream) {
    const float* brushes = (const float*)d_in[0];   // (16, 64, 2) f32
    const float* patches = (const float*)d_in[1];   // (16, 64, 3, 32, 32) f32
    float* out = (float*)d_out;                     // (16, 3, 256, 256) f32

    char* ws = (char*)d_ws;
    float2* gxy  = (float2*)(ws + WS_GXY_OFF);
    float*  t_ws = (float*) (ws + WS_T_OFF);
    float*  fy_ws= (float*) (ws + WS_FY_OFF);

    norm_kernel<<<NB, 64, 0, stream>>>(brushes, gxy);
    precomp_kernel<<<NB * NN, 128, 0, stream>>>(patches, gxy, t_ws, fy_ws);
    gather_kernel<<<NB * TX_N * TY_N, 192, 0, stream>>>(gxy, t_ws, fy_ws, out);
}

// Round 5
// 40.294 us; speedup vs baseline: 3.2680x; 3.2680x over previous
//
#include <hip/hip_runtime.h>

#define IMG_W 256
#define IMG_H 256
#define EPSN 1e-7f
#define INV_SIG2 50.0f      // 1 / (2 * 0.1^2)
#define NB 16               // batch
#define NN 64               // strokes per image
#define NC 3                // channels
#define PH 32
#define PW 32
#define WIN 36              // stroke footprint window (all nonzero f32 taps)
#define ROWP 36             // LDS patch row stride (144B, 16B-aligned)
#define TST 36              // t_ws xl-dim stride

#define TILE_W 64
#define TILE_H 8
#define TPI ((IMG_W / TILE_W) * (IMG_H / TILE_H))   // 128 tiles per image
#define NWG (NB * TPI)                              // 2048 gather blocks

// ws layout (bytes)
#define WS_GXY 0                                    // float2[1024]
#define WS_T   8192                                 // t[1024][3][32][36] f32
#define WS_T_BYTES ((size_t)NB * NN * NC * PH * TST * 4)
#define WS_FYW (WS_T + WS_T_BYTES)                  // float4[1024][36]
#define WS_FYW_BYTES ((size_t)NB * NN * WIN * 16)
#define WS_FYP (WS_FYW + WS_FYW_BYTES)              // int[1024][36]

// ---------------- kernel 1: per-stroke precompute (norm fused) -------------
// t[p][xl] = sum of 4 Fx taps * patch ; fyw/fyp0 = compact 4-tap Fy rows.
__global__ __launch_bounds__(128)
void precomp_kernel(const float* __restrict__ brushes,
                    const float* __restrict__ patches,
                    float2* __restrict__ gxy,
                    float* __restrict__ t_ws,
                    float4* __restrict__ fyw,
                    int* __restrict__ fyp0) {
    __shared__ float patch_s[NC][PH][ROWP];
    __shared__ float den_x[PW];
    __shared__ float den_y[PH];
    __shared__ float g_s[2];

    const int blk = blockIdx.x;               // stroke index b*64+n
    const int b   = blk >> 6;
    const int n   = blk & 63;
    const int tid = threadIdx.x;
    const float* P = patches + (size_t)blk * (NC * PH * PW);

    // fused per-image min/max normalization (wave 0)
    if (tid < 64) {
        float2 v = ((const float2*)brushes)[b * NN + tid];
        float mnx = v.x, mxx = v.x, mny = v.y, mxy = v.y;
        #pragma unroll
        for (int off = 32; off > 0; off >>= 1) {
            mnx = fminf(mnx, __shfl_xor(mnx, off));
            mxx = fmaxf(mxx, __shfl_xor(mxx, off));
            mny = fminf(mny, __shfl_xor(mny, off));
            mxy = fmaxf(mxy, __shfl_xor(mxy, off));
        }
        if (tid == n) {
            float gx = (v.x - mnx) / (mxx - mnx + EPSN) * (float)IMG_W;
            float gy = (v.y - mny) / (mxy - mny + EPSN) * (float)IMG_H;
            g_s[0] = gx; g_s[1] = gy;
            gxy[blk] = make_float2(gx, gy);
        }
    }

    // stage patch -> LDS (float4, 16B-aligned rows)
    for (int i = tid; i < NC * PH * PW / 4; i += 128) {
        float4 v = ((const float4*)P)[i];
        int base = i * 4;
        int c = base >> 10;
        int r = base & 1023;
        int p = r >> 5, q = r & 31;
        *(float4*)&patch_s[c][p][q] = v;
    }
    __syncthreads();

    const float gx = g_s[0];
    const float gy = g_s[1];
    const int ix0 = (int)floorf(gx) - 17;
    const int iy0 = (int)floorf(gy) - 17;

    // normalization denominators (4 taps hold all nonzero f32 terms)
    if (tid < PW) {
        float cx = gx + (float)tid - 15.5f;   // ux_q = gx + (q+1) - 16.5
        int f = (int)floorf(cx);
        float s = 0.f;
        #pragma unroll
        for (int t = -1; t <= 2; ++t) {
            int a = f + t;
            if (a >= -16 && a <= IMG_W + 15) {
                float d = (float)a - cx;
                s += expf(-(d * d) * INV_SIG2);
            }
        }
        den_x[tid] = 1.f / (s + EPSN);
    } else if (tid < 2 * PW) {
        int p = tid - PW;
        float cy = gy + (float)p - 15.4f;     // uy_p = gy + (p+1) - 16.4
        int f = (int)floorf(cy);
        float s = 0.f;
        #pragma unroll
        for (int t = -1; t <= 2; ++t) {
            int a = f + t;
            if (a >= -16 && a <= IMG_H + 15) {
                float d = (float)a - cy;
                s += expf(-(d * d) * INV_SIG2);
            }
        }
        den_y[p] = 1.f / (s + EPSN);
    }
    __syncthreads();

    // compact Fy rows: 4-tap weights + p0 (scaled by den_y and 1/N)
    if (tid < WIN) {
        float z = (float)(iy0 + tid) - gy + 15.4f;    // = z - p at tap p
        int p0 = min(max((int)floorf(z) - 1, 0), PH - 4);
        float4 w;
        float d0 = z - (float)(p0 + 0);
        float d1 = z - (float)(p0 + 1);
        float d2 = z - (float)(p0 + 2);
        float d3 = z - (float)(p0 + 3);
        w.x = expf(-(d0 * d0) * INV_SIG2) * den_y[p0 + 0] * (1.0f / NN);
        w.y = expf(-(d1 * d1) * INV_SIG2) * den_y[p0 + 1] * (1.0f / NN);
        w.z = expf(-(d2 * d2) * INV_SIG2) * den_y[p0 + 2] * (1.0f / NN);
        w.w = expf(-(d3 * d3) * INV_SIG2) * den_y[p0 + 3] * (1.0f / NN);
        fyw[blk * WIN + tid]  = w;
        fyp0[blk * WIN + tid] = p0;
    }

    // stage C, 4-tap: thread owns (c, xl); t stored [p][xl] (gather-coalesced)
    if (tid < NC * WIN) {
        const int cc = tid / WIN;
        const int xl = tid - cc * WIN;
        float zx = (float)(ix0 + xl) - gx + 15.5f;    // = zx - q at tap q
        int q0 = min(max((int)floorf(zx) - 1, 0), PW - 4);
        float e0 = zx - (float)(q0 + 0);
        float e1 = zx - (float)(q0 + 1);
        float e2 = zx - (float)(q0 + 2);
        float e3 = zx - (float)(q0 + 3);
        float w0 = expf(-(e0 * e0) * INV_SIG2) * den_x[q0 + 0];
        float w1 = expf(-(e1 * e1) * INV_SIG2) * den_x[q0 + 1];
        float w2 = expf(-(e2 * e2) * INV_SIG2) * den_x[q0 + 2];
        float w3 = expf(-(e3 * e3) * INV_SIG2) * den_x[q0 + 3];

        const float* pr = &patch_s[cc][0][q0];
        float* tb = t_ws + ((size_t)blk * NC + cc) * PH * TST + xl;
        #pragma unroll
        for (int p = 0; p < PH; ++p) {
            float s = w0 * pr[p * ROWP + 0] + w1 * pr[p * ROWP + 1]
                    + w2 * pr[p * ROWP + 2] + w3 * pr[p * ROWP + 3];
            tb[p * TST] = s;
        }
    }
}

// ---------------- kernel 2: gather per 64x8 tile, ballot stroke list -------
__global__ __launch_bounds__(192)
void gather_kernel(const float2* __restrict__ gxy,
                   const float* __restrict__ t_ws,
                   const float4* __restrict__ fyw,
                   const int* __restrict__ fyp0,
                   float* __restrict__ out) {
    __shared__ int sPack[NN];
    __shared__ int sCnt;

    // XCD-contiguous swizzle: XCD k gets tiles [k*256, (k+1)*256) = 2 images
    int blk = blockIdx.x;
    blk = (blk & 7) * (NWG >> 3) + (blk >> 3);

    const int b   = blk >> 7;                 // image
    const int t7  = blk & 127;
    const int ty0 = (t7 >> 2) * TILE_H;
    const int tx0 = (t7 & 3) * TILE_W;
    const int tid = threadIdx.x;
    const int cc  = tid >> 6;                 // channel
    const int xg  = tx0 + (tid & 63);         // owned x column

    // wave 0: ballot-compacted overlap list (deterministic, O(1))
    if (tid < 64) {
        float2 g = gxy[b * NN + tid];
        int ix0 = (int)floorf(g.x) - 17;
        int iy0 = (int)floorf(g.y) - 17;
        bool ov = (ix0 <= tx0 + TILE_W - 1) && (ix0 + WIN - 1 >= tx0) &&
                  (iy0 <= ty0 + TILE_H - 1) && (iy0 + WIN - 1 >= ty0);
        unsigned long long m = __ballot(ov);
        if (ov) {
            int pos = __popcll(m & ((1ull << tid) - 1));
            sPack[pos] = tid | ((ix0 + 17) << 6) | ((iy0 + 17) << 15);
        }
        if (tid == 0) sCnt = (int)__popcll(m);
    }
    __syncthreads();
    const int cnt = sCnt;

    float acc[TILE_H];
    #pragma unroll
    for (int i = 0; i < TILE_H; ++i) acc[i] = 0.f;

    for (int i = 0; i < cnt; ++i) {
        const int pk  = sPack[i];
        const int n   = pk & 63;
        const int ix0 = ((pk >> 6) & 511) - 17;
        const int iy0 = ((pk >> 15) & 511) - 17;
        const int s   = b * NN + n;

        const int xl = xg - ix0;
        if ((unsigned)xl >= (unsigned)WIN) continue;

        const float*  tb = t_ws + ((size_t)s * NC + cc) * PH * TST + xl;
        const float4* fw = fyw + s * WIN;
        const int*    fp = fyp0 + s * WIN;

        #pragma unroll
        for (int yi = 0; yi < TILE_H; ++yi) {
            int yl = ty0 + yi - iy0;          // block-uniform
            if ((unsigned)yl < (unsigned)WIN) {
                int p0   = fp[yl];            // broadcast
                float4 w = fw[yl];            // broadcast
                const float* tp = tb + p0 * TST;
                acc[yi] += w.x * tp[0]  + w.y * tp[TST]
                         + w.z * tp[2 * TST] + w.w * tp[3 * TST];
            }
        }
    }

    // coalesced final store; tiles partition the image -> no atomics/fill
    float* o = out + (((size_t)b * NC + cc) * IMG_H + ty0) * IMG_W + xg;
    #pragma unroll
    for (int yi = 0; yi < TILE_H; ++yi)
        o[(size_t)yi * IMG_W] = acc[yi];
}

extern "C" void kernel_launch(void* const* d_in, const int* in_sizes, int n_in,
                              void* d_out, int out_size, void* d_ws, size_t ws_size,
                              hipStream_t stream) {
    const float* brushes = (const float*)d_in[0];   // (16, 64, 2) f32
    const float* patches = (const float*)d_in[1];   // (16, 64, 3, 32, 32) f32
    float* out = (float*)d_out;                     // (16, 3, 256, 256) f32

    char* ws = (char*)d_ws;
    float2* gxy   = (float2*)(ws + WS_GXY);
    float*  t_ws  = (float*) (ws + WS_T);
    float4* fyw   = (float4*)(ws + WS_FYW);
    int*    fyp0  = (int*)   (ws + WS_FYP);

    precomp_kernel<<<NB * NN, 128, 0, stream>>>(brushes, patches, gxy,
                                                t_ws, fyw, fyp0);
    gather_kernel<<<NWG, 192, 0, stream>>>(gxy, t_ws, fyw, fyp0, out);
}